// Round 11
// baseline (5403.158 us; speedup 1.0000x reference)
//
#include <hip/hip_runtime.h>
#include <stdint.h>

// Problem constants
#define B_  256
#define S_  512
#define E_  100
#define H_  512
#define G_  2048          // 4H
#define KH_ 512

typedef _Float16 half8 __attribute__((ext_vector_type(8)));
typedef float    f32x4 __attribute__((ext_vector_type(4)));
union V16 { f32x4 f; half8 h; unsigned long long q[2]; };

// ws layout (bytes)
#define OFF_WC   0u          // Wc [c16][w4][n2][s20][L64][e8] f16 : 2,621,440
#define OFF_HB2  2621440u    // hb2 [2 parity][16 r][16KB tile] u32 : 524,288
#define OFF_FLG  3145728u    // flg [16 r][64] u32 (per-wave flags) : 4,096
#define OFF_XB3  3149824u    // xb3 [t512][rg16][j3][L64][e8] f16   : 25,165,824
#define OFF_XTL  28315648u   // xtl [t512][b256][e4] f16            : 1,048,576
#define OFF_BIAS 29364224u   // [G] f32                             : 8,192
#define WS_NEED  29372416u

// LDS carve (dynamic) — full W h-part in LDS (r7 config)
#define LDS_W   131072       // [w4][n2][kt16][L64][16B]
#define LDS_A   16384        // h A-tile [16 rows][512 halfs], XOR-swizzled
#define LDS_G   8448         // float[4][16][33]
#define LDS_TOT (LDS_W + LDS_A + LDS_G)   // 155,904

// ---------------------------------------------------------------- prep: W (fragment-major) + bias
__global__ void prep_wc4(const float* __restrict__ Wih, const float* __restrict__ Whh,
                         const float* __restrict__ bih, const float* __restrict__ bhh,
                         _Float16* __restrict__ Wc, float* __restrict__ bias) {
    int idx = blockIdx.x * 256 + threadIdx.x;     // < 1,310,720
    int e  = idx & 7;
    int L  = (idx >> 3) & 63;
    int q  = idx >> 9;                            // < 2560
    int s  = q % 20;
    int qq = q / 20;
    int n  = qq & 1;
    int w  = (qq >> 1) & 3;
    int c  = qq >> 3;
    int g  = (w << 9) + (c << 5) + (n << 4) + (L & 15);
    int kl = ((L >> 4) << 3) + e;
    float v = 0.f;
    if (s < 16) {
        v = Whh[g * KH_ + (s << 5) + kl];
    } else {
        int xk = (s < 19) ? ((s - 16) << 5) + kl : 96 + kl;
        if (xk < E_) v = Wih[g * E_ + xk];
    }
    Wc[idx] = (_Float16)v;
    if (idx < G_) bias[idx] = bih[idx] + bhh[idx];
}

// ---------------------------------------------------------------- prep: x main (k 0..95, fragment-major)
__global__ void prep_x3(const int* __restrict__ sent, const float* __restrict__ emb,
                        _Float16* __restrict__ xb3) {
    size_t idx = (size_t)blockIdx.x * 256 + threadIdx.x;   // < 12,582,912
    int e  = (int)(idx & 7);
    int L  = (int)((idx >> 3) & 63);
    int q  = (int)(idx >> 9);
    int j  = q % 3;
    int qq = q / 3;
    int rg = qq & 15;
    int t  = qq >> 4;
    int b  = (rg << 4) + (L & 15);
    int k  = (j << 5) + ((L >> 4) << 3) + e;     // < 96 < E_
    int tok = sent[b * S_ + t];
    xb3[idx] = (_Float16)emb[(size_t)tok * E_ + k];
}

// ---------------------------------------------------------------- prep: x tail (k 96..99)
__global__ void prep_xtail(const int* __restrict__ sent, const float* __restrict__ emb,
                           _Float16* __restrict__ xtl) {
    int idx = blockIdx.x * 256 + threadIdx.x;    // < 524,288
    int e = idx & 3;
    int b = (idx >> 2) & 255;
    int t = idx >> 10;
    int tok = sent[b * S_ + t];
    xtl[idx] = (_Float16)emb[(size_t)tok * E_ + 96 + e];
}

// ---------------------------------------------------------------- persistent LSTM
// 256 blocks = 16 rows x 16 hcol-tiles; W h-part in LDS. Sync redesign vs r7:
//  - producers: 64 coalesced u32 h-stores per wave (dense 16KB/row tile),
//    then per-wave RELEASE flag (drains that wave's vmcnt; no extra barrier).
//  - consumers: poll ONLY the row's 64-flag block (256B, 1 coalesced
//    request/wave/round -> no LLC bandwidth self-congestion), then ONE bulk
//    read: 4x global_load_dwordx4 sc0 sc1 (LLC-direct, 64B/thread coalesced,
//    waitcnt inside the asm), staged to XOR-swizzled LDS.
//  - ordering: each wave's data reads are control-dependent on ITS own poll
//    (r4-proven); parity double-buffer kills overwrite races; flags monotone.
__global__ __launch_bounds__(256, 1) void lstm_persist(
    const _Float16* __restrict__ Wc, unsigned* __restrict__ hb2,
    unsigned* __restrict__ flg,
    const _Float16* __restrict__ xb3, const _Float16* __restrict__ xtl,
    const float* __restrict__ bias, float* __restrict__ out)
{
    extern __shared__ __align__(16) char smem[];
    char* wl = smem;                       // W h-part fragments
    char* al = smem + LDS_W;               // A tile (swizzled)
    float (*gbuf)[16][33] = reinterpret_cast<float(*)[16][33]>(smem + LDS_W + LDS_A);

    const int tid = threadIdx.x;
    const int L   = tid & 63;
    const int w   = tid >> 6;              // wave = gate type (0:i 1:f 2:g 3:o)
    const int bx  = blockIdx.x;
    const int xcd = bx & 7;                // XCD-aware swizzle (perf heuristic)
    const int kk_ = bx >> 3;
    const int r   = (xcd << 1) | (kk_ >> 4);   // batch-row 0..15
    const int c   = kk_ & 15;                  // hcol-tile 0..15
    const int brow0 = r << 4;
    const int hcol0 = c << 5;

    // ---- W preload: slots 0..15 (h) -> LDS; slots 16..19 (x) -> regs
    const _Float16* wp0 = Wc + (size_t)((((c << 2) + w) << 1)) * (20 * 512) + (L << 3);
    const _Float16* wp1 = wp0 + 20 * 512;
#pragma unroll
    for (int n = 0; n < 2; ++n)
#pragma unroll
        for (int kt = 0; kt < 16; ++kt) {
            f32x4 v = *reinterpret_cast<const f32x4*>((n ? wp1 : wp0) + (kt << 9));
            *reinterpret_cast<f32x4*>(wl + ((((w << 1) + n) * 16 + kt) << 10) + (L << 4)) = v;
        }
    V16 wx[2][4];
#pragma unroll
    for (int n = 0; n < 2; ++n)
#pragma unroll
        for (int j = 0; j < 4; ++j)
            wx[n][j].f = *reinterpret_cast<const f32x4*>((n ? wp1 : wp0) + ((16 + j) << 9));

    // ---- per-thread cell-state mapping: thread owns h/c at (bl, j0), (bl, j0+1)
    const int bl = tid >> 4;
    const int j0 = (tid << 1) & 31;
    const float bi0 = bias[hcol0 + j0],         bi1 = bias[hcol0 + j0 + 1];
    const float bf0 = bias[512  + hcol0 + j0],  bf1 = bias[512  + hcol0 + j0 + 1];
    const float bg0 = bias[1024 + hcol0 + j0],  bg1 = bias[1024 + hcol0 + j0 + 1];
    const float bo0 = bias[1536 + hcol0 + j0],  bo1 = bias[1536 + hcol0 + j0 + 1];
    float cc0 = 0.f, cc1 = 0.f;

    const int arow = L & 15;
    const int agrp = L >> 4;
    const int ard  = arow << 10;
    const int asw  = (arow & 7) << 4;

    // consumer staging geometry: wave w stages rows 4w..4w+3, 64B/thread
    const int rowl = (w << 2) + (L >> 4);
    const int lsw  = ((L & 15) ^ (rowl & 7)) << 4;

    // ---- x fragments for t=0 (3 main tiles + tail tile)
    V16 xf[3], xt;
    {
        const _Float16* xp = xb3 + ((size_t)r * 3) * 512 + (L << 3);
#pragma unroll
        for (int j = 0; j < 3; ++j) xf[j].f = *reinterpret_cast<const f32x4*>(xp + j * 512);
        unsigned long long tv = *reinterpret_cast<const unsigned long long*>(
            xtl + (size_t)(brow0 + arow) * 4);
        xt.q[0] = (agrp == 0) ? tv : 0ull;
        xt.q[1] = 0ull;
    }

    for (int t = 0; t < S_; ++t) {
        // ---- 1. x-part MFMA (4 tiles; independent of h)
        f32x4 a00 = {0,0,0,0}, a01 = {0,0,0,0}, a10 = {0,0,0,0}, a11 = {0,0,0,0};
#pragma unroll
        for (int j = 0; j < 4; ++j) {
            half8 a = (j < 3) ? xf[j].h : xt.h;
            if (j & 1) {
                a01 = __builtin_amdgcn_mfma_f32_16x16x32_f16(a, wx[0][j].h, a01, 0, 0, 0);
                a11 = __builtin_amdgcn_mfma_f32_16x16x32_f16(a, wx[1][j].h, a11, 0, 0, 0);
            } else {
                a00 = __builtin_amdgcn_mfma_f32_16x16x32_f16(a, wx[0][j].h, a00, 0, 0, 0);
                a10 = __builtin_amdgcn_mfma_f32_16x16x32_f16(a, wx[1][j].h, a10, 0, 0, 0);
            }
        }

        // ---- 2. compact flag poll (1 line-set/round) + ONE bulk coalesced h read
        if (t > 0) {
            const unsigned tag = (unsigned)t;
            const unsigned* fl = flg + (r << 6);
            int rounds = 0;
            for (;;) {
                unsigned fv = __hip_atomic_load(fl + L, __ATOMIC_RELAXED,
                                                __HIP_MEMORY_SCOPE_AGENT);
                if (__all(fv >= tag)) break;
                if (++rounds > 20000000) break;      // safety valve
            }
            __builtin_amdgcn_sched_barrier(0);
            // bulk read: this wave's 4 rows, 64B/thread contiguous, LLC-direct
            const char* hbase = (const char*)hb2 + ((size_t)(t & 1) << 18)
                              + ((size_t)r << 14) + (rowl << 10) + ((L & 15) << 4);
            V16 h0_, h1_, h2_, h3_;
            asm volatile(
                "global_load_dwordx4 %0, %4, off sc0 sc1\n\t"
                "global_load_dwordx4 %1, %4, off offset:256 sc0 sc1\n\t"
                "global_load_dwordx4 %2, %4, off offset:512 sc0 sc1\n\t"
                "global_load_dwordx4 %3, %4, off offset:768 sc0 sc1\n\t"
                "s_waitcnt vmcnt(0)"
                : "=&v"(h0_.f), "=&v"(h1_.f), "=&v"(h2_.f), "=&v"(h3_.f)
                : "v"(hbase)
                : "memory");
            __builtin_amdgcn_sched_barrier(0);
            // stage to XOR-swizzled LDS: granule (L&15)+16i at pos ^ (rowl&7)
            char* lb = al + (rowl << 10) + lsw;
            *reinterpret_cast<f32x4*>(lb +   0) = h0_.f;
            *reinterpret_cast<f32x4*>(lb + 256) = h1_.f;
            *reinterpret_cast<f32x4*>(lb + 512) = h2_.f;
            *reinterpret_cast<f32x4*>(lb + 768) = h3_.f;
        }
        __syncthreads();                   // barrier 1: A tile ready

        // ---- 3. h-part MFMA: A from swizzled LDS, B from LDS
        if (t > 0) {
#pragma unroll
            for (int kt = 0; kt < 16; ++kt) {
                V16 av, b0, b1;
                av.f = *reinterpret_cast<const f32x4*>(
                    al + ard + ((((kt << 2) + agrp) << 4) ^ asw));
                b0.f = *reinterpret_cast<const f32x4*>(wl + (((w << 5) + kt) << 10) + (L << 4));
                b1.f = *reinterpret_cast<const f32x4*>(wl + (((w << 5) + 16 + kt) << 10) + (L << 4));
                if (kt & 1) {
                    a01 = __builtin_amdgcn_mfma_f32_16x16x32_f16(av.h, b0.h, a01, 0, 0, 0);
                    a11 = __builtin_amdgcn_mfma_f32_16x16x32_f16(av.h, b1.h, a11, 0, 0, 0);
                } else {
                    a00 = __builtin_amdgcn_mfma_f32_16x16x32_f16(av.h, b0.h, a00, 0, 0, 0);
                    a10 = __builtin_amdgcn_mfma_f32_16x16x32_f16(av.h, b1.h, a10, 0, 0, 0);
                }
            }
        }
        f32x4 g0 = a00 + a01;
        f32x4 g1 = a10 + a11;
        {
            const int grb = agrp << 2;     // C/D: col=lane&15, row=(lane>>4)*4+reg
            const int gc  = L & 15;
#pragma unroll
            for (int rr = 0; rr < 4; ++rr) {
                gbuf[w][grb + rr][gc]      = g0[rr];
                gbuf[w][grb + rr][16 + gc] = g1[rr];
            }
        }

        // ---- 4. prefetch next step's x fragments (land during barrier+elementwise)
        V16 xn[3], xnt;
        {
            const int tn = (t + 1) & (S_ - 1);
            const _Float16* xp = xb3 + (((size_t)tn * 16 + r) * 3) * 512 + (L << 3);
#pragma unroll
            for (int j = 0; j < 3; ++j) xn[j].f = *reinterpret_cast<const f32x4*>(xp + j * 512);
            unsigned long long tv = *reinterpret_cast<const unsigned long long*>(
                xtl + ((size_t)tn * 256 + brow0 + arow) * 4);
            xnt.q[0] = (agrp == 0) ? tv : 0ull;
            xnt.q[1] = 0ull;
        }
        __syncthreads();                   // barrier 2: gates ready

        // ---- 5. elementwise cell update + publish (u32 stores + per-wave release flag)
        float i0 = gbuf[0][bl][j0]     + bi0, i1 = gbuf[0][bl][j0 + 1] + bi1;
        float f0 = gbuf[1][bl][j0]     + bf0, f1 = gbuf[1][bl][j0 + 1] + bf1;
        float gg0= gbuf[2][bl][j0]     + bg0, gg1= gbuf[2][bl][j0 + 1] + bg1;
        float o0 = gbuf[3][bl][j0]     + bo0, o1 = gbuf[3][bl][j0 + 1] + bo1;
        float si0 = 1.f / (1.f + __expf(-i0));
        float sf0 = 1.f / (1.f + __expf(-f0));
        float so0 = 1.f / (1.f + __expf(-o0));
        float tg0 = tanhf(gg0);
        float si1 = 1.f / (1.f + __expf(-i1));
        float sf1 = 1.f / (1.f + __expf(-f1));
        float so1 = 1.f / (1.f + __expf(-o1));
        float tg1 = tanhf(gg1);
        cc0 = sf0 * cc0 + si0 * tg0;
        cc1 = sf1 * cc1 + si1 * tg1;
        float h0 = so0 * tanhf(cc0);
        float h1 = so1 * tanhf(cc1);

        if (t == S_ - 1) {
            float* op = out + (size_t)(brow0 + bl) * H_ + hcol0 + j0;
            op[0] = h0; op[1] = h1;
        } else {
            _Float16 hh0 = (_Float16)h0, hh1 = (_Float16)h1;
            unsigned pack = ((unsigned)*(unsigned short*)&hh1 << 16)
                          |  (unsigned)*(unsigned short*)&hh0;
            // dense tile: [parity][r][bl(16)][256 u32]; this thread -> (bl, c*16+(tid&15))
            unsigned* hp = hb2 + ((size_t)((t + 1) & 1) << 16) + ((size_t)r << 12)
                         + (bl << 8) + (c << 4) + (tid & 15);
            __hip_atomic_store(hp, pack, __ATOMIC_RELAXED, __HIP_MEMORY_SCOPE_AGENT);
            // per-wave release flag: drains THIS wave's h-stores, then flags
            if (L == 0)
                __hip_atomic_store(flg + (r << 6) + (c << 2) + w, (unsigned)(t + 1),
                                   __ATOMIC_RELEASE, __HIP_MEMORY_SCOPE_AGENT);
        }

        // rotate x prefetch
#pragma unroll
        for (int j = 0; j < 3; ++j) xf[j] = xn[j];
        xt = xnt;
    }
}

// ---------------------------------------------------------------- launch
extern "C" void kernel_launch(void* const* d_in, const int* in_sizes, int n_in,
                              void* d_out, int out_size, void* d_ws, size_t ws_size,
                              hipStream_t stream) {
    (void)in_sizes; (void)n_in; (void)out_size;
    if (ws_size < WS_NEED) return;

    const int*   sent = (const int*)d_in[0];
    const float* emb  = (const float*)d_in[1];
    const float* Wih  = (const float*)d_in[2];
    const float* Whh  = (const float*)d_in[3];
    const float* bih  = (const float*)d_in[4];
    const float* bhh  = (const float*)d_in[5];

    char* ws = (char*)d_ws;
    _Float16* Wc   = (_Float16*)(ws + OFF_WC);
    unsigned* hb2  = (unsigned*)(ws + OFF_HB2);
    unsigned* flg  = (unsigned*)(ws + OFF_FLG);
    _Float16* xb3  = (_Float16*)(ws + OFF_XB3);
    _Float16* xtl  = (_Float16*)(ws + OFF_XTL);
    float*    bias = (float*)(ws + OFF_BIAS);

    (void)hipFuncSetAttribute(reinterpret_cast<const void*>(lstm_persist),
                              hipFuncAttributeMaxDynamicSharedMemorySize, LDS_TOT);

    (void)hipMemsetAsync(flg, 0, 16 * 64 * sizeof(unsigned), stream);

    prep_wc4<<<(16 * 4 * 2 * 20 * 64 * 8) / 256, 256, 0, stream>>>(Wih, Whh, bih, bhh, Wc, bias);
    prep_x3<<<(S_ * 16 * 3 * 512) / 256, 256, 0, stream>>>(sent, emb, xb3);
    prep_xtail<<<(S_ * B_ * 4) / 256, 256, 0, stream>>>(sent, emb, xtl);
    lstm_persist<<<256, 256, LDS_TOT, stream>>>(Wc, hb2, flg, xb3, xtl, bias, (float*)d_out);
}

// Round 12
// 1285.762 us; speedup vs baseline: 4.2023x; 4.2023x over previous
//
#include <hip/hip_runtime.h>
#include <stdint.h>

// Problem constants
#define B_  256
#define S_  512
#define E_  100
#define H_  512
#define G_  2048          // 4H
#define KH_ 512

typedef _Float16 half8 __attribute__((ext_vector_type(8)));
typedef float    f32x4 __attribute__((ext_vector_type(4)));
union V16 { f32x4 f; half8 h; unsigned long long q[2]; };

// ws layout (bytes)
#define OFF_WC   0u          // Wc [c16][w4][n2][s20][L64][e8] f16 : 2,621,440
#define OFF_HBT  2621440u    // hbt [2][256 b][256 cp] u64 tagged-h : 1,048,576
#define OFF_XB3  3670016u    // xb3 [t512][rg16][j3][L64][e8] f16   : 25,165,824
#define OFF_XTL  28835840u   // xtl [t512][b256][e4] f16            : 1,048,576
#define OFF_BIAS 29884416u   // [G] f32                             : 8,192
#define WS_NEED  29892608u

// LDS carve (dynamic) — full W h-part in LDS
#define LDS_W   131072       // [w4][n2][kt16][L64][16B]
#define LDS_A   16384        // h A-tile [16 rows][512 halfs], XOR-swizzled
#define LDS_G   8448         // float[4][16][33]
#define LDS_TOT (LDS_W + LDS_A + LDS_G)   // 155,904

// ---------------------------------------------------------------- prep: W (fragment-major) + bias
__global__ void prep_wc4(const float* __restrict__ Wih, const float* __restrict__ Whh,
                         const float* __restrict__ bih, const float* __restrict__ bhh,
                         _Float16* __restrict__ Wc, float* __restrict__ bias) {
    int idx = blockIdx.x * 256 + threadIdx.x;     // < 1,310,720
    int e  = idx & 7;
    int L  = (idx >> 3) & 63;
    int q  = idx >> 9;                            // < 2560
    int s  = q % 20;
    int qq = q / 20;
    int n  = qq & 1;
    int w  = (qq >> 1) & 3;
    int c  = qq >> 3;
    int g  = (w << 9) + (c << 5) + (n << 4) + (L & 15);
    int kl = ((L >> 4) << 3) + e;
    float v = 0.f;
    if (s < 16) {
        v = Whh[g * KH_ + (s << 5) + kl];
    } else {
        int xk = (s < 19) ? ((s - 16) << 5) + kl : 96 + kl;
        if (xk < E_) v = Wih[g * E_ + xk];
    }
    Wc[idx] = (_Float16)v;
    if (idx < G_) bias[idx] = bih[idx] + bhh[idx];
}

// ---------------------------------------------------------------- prep: x main (k 0..95, fragment-major)
__global__ void prep_x3(const int* __restrict__ sent, const float* __restrict__ emb,
                        _Float16* __restrict__ xb3) {
    size_t idx = (size_t)blockIdx.x * 256 + threadIdx.x;   // < 12,582,912
    int e  = (int)(idx & 7);
    int L  = (int)((idx >> 3) & 63);
    int q  = (int)(idx >> 9);
    int j  = q % 3;
    int qq = q / 3;
    int rg = qq & 15;
    int t  = qq >> 4;
    int b  = (rg << 4) + (L & 15);
    int k  = (j << 5) + ((L >> 4) << 3) + e;     // < 96 < E_
    int tok = sent[b * S_ + t];
    xb3[idx] = (_Float16)emb[(size_t)tok * E_ + k];
}

// ---------------------------------------------------------------- prep: x tail (k 96..99)
__global__ void prep_xtail(const int* __restrict__ sent, const float* __restrict__ emb,
                           _Float16* __restrict__ xtl) {
    int idx = blockIdx.x * 256 + threadIdx.x;    // < 524,288
    int e = idx & 3;
    int b = (idx >> 2) & 255;
    int t = idx >> 10;
    int tok = sent[b * S_ + t];
    xtl[idx] = (_Float16)emb[(size_t)tok * E_ + 96 + e];
}

// ---------------------------------------------------------------- persistent LSTM
// r7 structure (proven 1304us) + ONE change: B-fragments kt 0..7 preread from
// LDS into registers during the poll window (idle LDS port), shortening the
// post-barrier h-MFMA phase. Everything else identical: fused tagged u64
// publish (fire-and-forget, no drains anywhere), retry-validate consume.
__global__ __launch_bounds__(256, 1) void lstm_persist(
    const _Float16* __restrict__ Wc, unsigned long long* __restrict__ hbt,
    const _Float16* __restrict__ xb3, const _Float16* __restrict__ xtl,
    const float* __restrict__ bias, float* __restrict__ out)
{
    extern __shared__ __align__(16) char smem[];
    char* wl = smem;                       // W h-part fragments
    char* al = smem + LDS_W;               // A tile (swizzled)
    float (*gbuf)[16][33] = reinterpret_cast<float(*)[16][33]>(smem + LDS_W + LDS_A);

    const int tid = threadIdx.x;
    const int L   = tid & 63;
    const int w   = tid >> 6;              // wave = gate type (0:i 1:f 2:g 3:o)
    const int bx  = blockIdx.x;
    const int xcd = bx & 7;                // XCD-aware swizzle (perf heuristic)
    const int kk_ = bx >> 3;
    const int r   = (xcd << 1) | (kk_ >> 4);   // batch-row 0..15
    const int c   = kk_ & 15;                  // hcol-tile 0..15
    const int brow0 = r << 4;
    const int hcol0 = c << 5;

    // ---- W preload: slots 0..15 (h) -> LDS; slots 16..19 (x) -> regs
    const _Float16* wp0 = Wc + (size_t)((((c << 2) + w) << 1)) * (20 * 512) + (L << 3);
    const _Float16* wp1 = wp0 + 20 * 512;
#pragma unroll
    for (int n = 0; n < 2; ++n)
#pragma unroll
        for (int kt = 0; kt < 16; ++kt) {
            f32x4 v = *reinterpret_cast<const f32x4*>((n ? wp1 : wp0) + (kt << 9));
            *reinterpret_cast<f32x4*>(wl + ((((w << 1) + n) * 16 + kt) << 10) + (L << 4)) = v;
        }
    V16 wx[2][4];
#pragma unroll
    for (int n = 0; n < 2; ++n)
#pragma unroll
        for (int j = 0; j < 4; ++j)
            wx[n][j].f = *reinterpret_cast<const f32x4*>((n ? wp1 : wp0) + ((16 + j) << 9));

    // ---- per-thread cell-state mapping: thread owns h/c at (bl, j0), (bl, j0+1)
    const int bl = tid >> 4;
    const int j0 = (tid << 1) & 31;
    const float bi0 = bias[hcol0 + j0],         bi1 = bias[hcol0 + j0 + 1];
    const float bf0 = bias[512  + hcol0 + j0],  bf1 = bias[512  + hcol0 + j0 + 1];
    const float bg0 = bias[1024 + hcol0 + j0],  bg1 = bias[1024 + hcol0 + j0 + 1];
    const float bo0 = bias[1536 + hcol0 + j0],  bo1 = bias[1536 + hcol0 + j0 + 1];
    float cc0 = 0.f, cc1 = 0.f;

    const int arow = L & 15;
    const int agrp = L >> 4;
    const int ard  = arow << 10;
    const int asw  = (arow & 7) << 4;

    // ---- x fragments for t=0 (3 main tiles + tail tile)
    V16 xf[3], xt;
    {
        const _Float16* xp = xb3 + ((size_t)r * 3) * 512 + (L << 3);
#pragma unroll
        for (int j = 0; j < 3; ++j) xf[j].f = *reinterpret_cast<const f32x4*>(xp + j * 512);
        unsigned long long tv = *reinterpret_cast<const unsigned long long*>(
            xtl + (size_t)(brow0 + arow) * 4);
        xt.q[0] = (agrp == 0) ? tv : 0ull;
        xt.q[1] = 0ull;
    }

    for (int t = 0; t < S_; ++t) {
        // ---- 1. x-part MFMA (4 tiles; independent of h)
        f32x4 a00 = {0,0,0,0}, a01 = {0,0,0,0}, a10 = {0,0,0,0}, a11 = {0,0,0,0};
#pragma unroll
        for (int j = 0; j < 4; ++j) {
            half8 a = (j < 3) ? xf[j].h : xt.h;
            if (j & 1) {
                a01 = __builtin_amdgcn_mfma_f32_16x16x32_f16(a, wx[0][j].h, a01, 0, 0, 0);
                a11 = __builtin_amdgcn_mfma_f32_16x16x32_f16(a, wx[1][j].h, a11, 0, 0, 0);
            } else {
                a00 = __builtin_amdgcn_mfma_f32_16x16x32_f16(a, wx[0][j].h, a00, 0, 0, 0);
                a10 = __builtin_amdgcn_mfma_f32_16x16x32_f16(a, wx[1][j].h, a10, 0, 0, 0);
            }
        }

        V16 bp[8][2];                      // kt 0..7 B-frags (iteration-local)
        if (t > 0) {
            // ---- 2. B-fragment preread: uses the idle LDS port during the poll
#pragma unroll
            for (int kt = 0; kt < 8; ++kt) {
                bp[kt][0].f = *reinterpret_cast<const f32x4*>(
                    wl + (((w << 5) + kt) << 10) + (L << 4));
                bp[kt][1].f = *reinterpret_cast<const f32x4*>(
                    wl + (((w << 5) + 16 + kt) << 10) + (L << 4));
            }

            // ---- 3. retry-load tagged h words until tag==t, then stage to LDS
            const unsigned long long* hq = hbt + ((size_t)(t & 1) << 16) + ((size_t)brow0 << 8);
            const unsigned tag = (unsigned)t;
            unsigned long long vv[16];
            int rounds = 0;
            bool again = true;
            while (again) {
#pragma unroll
                for (int j = 0; j < 16; ++j)
                    vv[j] = __hip_atomic_load(hq + (j << 8) + tid,
                                              __ATOMIC_RELAXED, __HIP_MEMORY_SCOPE_AGENT);
                again = false;
#pragma unroll
                for (int j = 0; j < 16; ++j) again |= ((unsigned)vv[j] != tag);
                if (++rounds > 4000000) break;   // safety valve
            }
            __builtin_amdgcn_sched_barrier(0);
            // stage: row j, col-pair tid (u32 of 2 halfs), XOR-swizzled granules
#pragma unroll
            for (int j = 0; j < 16; ++j) {
                unsigned pack = (unsigned)(vv[j] >> 32);
                *reinterpret_cast<unsigned*>(
                    al + (j << 10) + ((((tid >> 2) ^ (j & 7))) << 4) + ((tid & 3) << 2)) = pack;
            }
        }
        __syncthreads();                   // barrier 1: A tile ready

        // ---- 4. h-part MFMA: A from swizzled LDS; B kt<8 from regs, kt>=8 from LDS
        if (t > 0) {
#pragma unroll
            for (int kt = 0; kt < 16; ++kt) {
                V16 av, b0, b1;
                av.f = *reinterpret_cast<const f32x4*>(
                    al + ard + ((((kt << 2) + agrp) << 4) ^ asw));
                if (kt < 8) {
                    b0 = bp[kt][0];
                    b1 = bp[kt][1];
                } else {
                    b0.f = *reinterpret_cast<const f32x4*>(
                        wl + (((w << 5) + kt) << 10) + (L << 4));
                    b1.f = *reinterpret_cast<const f32x4*>(
                        wl + (((w << 5) + 16 + kt) << 10) + (L << 4));
                }
                if (kt & 1) {
                    a01 = __builtin_amdgcn_mfma_f32_16x16x32_f16(av.h, b0.h, a01, 0, 0, 0);
                    a11 = __builtin_amdgcn_mfma_f32_16x16x32_f16(av.h, b1.h, a11, 0, 0, 0);
                } else {
                    a00 = __builtin_amdgcn_mfma_f32_16x16x32_f16(av.h, b0.h, a00, 0, 0, 0);
                    a10 = __builtin_amdgcn_mfma_f32_16x16x32_f16(av.h, b1.h, a10, 0, 0, 0);
                }
            }
        }
        f32x4 g0 = a00 + a01;
        f32x4 g1 = a10 + a11;
        {
            const int grb = agrp << 2;     // C/D: col=lane&15, row=(lane>>4)*4+reg
            const int gc  = L & 15;
#pragma unroll
            for (int rr = 0; rr < 4; ++rr) {
                gbuf[w][grb + rr][gc]      = g0[rr];
                gbuf[w][grb + rr][16 + gc] = g1[rr];
            }
        }

        // ---- 5. prefetch next step's x fragments (land during barrier+elementwise)
        V16 xn[3], xnt;
        {
            const int tn = (t + 1) & (S_ - 1);
            const _Float16* xp = xb3 + (((size_t)tn * 16 + r) * 3) * 512 + (L << 3);
#pragma unroll
            for (int j = 0; j < 3; ++j) xn[j].f = *reinterpret_cast<const f32x4*>(xp + j * 512);
            unsigned long long tv = *reinterpret_cast<const unsigned long long*>(
                xtl + ((size_t)tn * 256 + brow0 + arow) * 4);
            xnt.q[0] = (agrp == 0) ? tv : 0ull;
            xnt.q[1] = 0ull;
        }
        __syncthreads();                   // barrier 2: gates ready

        // ---- 6. elementwise cell update + tagged publish (fire-and-forget)
        float i0 = gbuf[0][bl][j0]     + bi0, i1 = gbuf[0][bl][j0 + 1] + bi1;
        float f0 = gbuf[1][bl][j0]     + bf0, f1 = gbuf[1][bl][j0 + 1] + bf1;
        float gg0= gbuf[2][bl][j0]     + bg0, gg1= gbuf[2][bl][j0 + 1] + bg1;
        float o0 = gbuf[3][bl][j0]     + bo0, o1 = gbuf[3][bl][j0 + 1] + bo1;
        float si0 = 1.f / (1.f + __expf(-i0));
        float sf0 = 1.f / (1.f + __expf(-f0));
        float so0 = 1.f / (1.f + __expf(-o0));
        float tg0 = tanhf(gg0);
        float si1 = 1.f / (1.f + __expf(-i1));
        float sf1 = 1.f / (1.f + __expf(-f1));
        float so1 = 1.f / (1.f + __expf(-o1));
        float tg1 = tanhf(gg1);
        cc0 = sf0 * cc0 + si0 * tg0;
        cc1 = sf1 * cc1 + si1 * tg1;
        float h0 = so0 * tanhf(cc0);
        float h1 = so1 * tanhf(cc1);

        if (t == S_ - 1) {
            float* op = out + (size_t)(brow0 + bl) * H_ + hcol0 + j0;
            op[0] = h0; op[1] = h1;
        } else {
            _Float16 hh0 = (_Float16)h0, hh1 = (_Float16)h1;
            unsigned pack = ((unsigned)*(unsigned short*)&hh1 << 16)
                          |  (unsigned)*(unsigned short*)&hh0;
            unsigned long long word = ((unsigned long long)pack << 32)
                                    |  (unsigned long long)(unsigned)(t + 1);
            __hip_atomic_store(hbt + ((size_t)((t + 1) & 1) << 16)
                                   + ((size_t)(brow0 + bl) << 8) + (c << 4) + (tid & 15),
                               word, __ATOMIC_RELAXED, __HIP_MEMORY_SCOPE_AGENT);
        }

        // rotate x prefetch
#pragma unroll
        for (int j = 0; j < 3; ++j) xf[j] = xn[j];
        xt = xnt;
    }
}

// ---------------------------------------------------------------- launch
extern "C" void kernel_launch(void* const* d_in, const int* in_sizes, int n_in,
                              void* d_out, int out_size, void* d_ws, size_t ws_size,
                              hipStream_t stream) {
    (void)in_sizes; (void)n_in; (void)out_size;
    if (ws_size < WS_NEED) return;

    const int*   sent = (const int*)d_in[0];
    const float* emb  = (const float*)d_in[1];
    const float* Wih  = (const float*)d_in[2];
    const float* Whh  = (const float*)d_in[3];
    const float* bih  = (const float*)d_in[4];
    const float* bhh  = (const float*)d_in[5];

    char* ws = (char*)d_ws;
    _Float16*           Wc   = (_Float16*)(ws + OFF_WC);
    unsigned long long* hbt  = (unsigned long long*)(ws + OFF_HBT);
    _Float16*           xb3  = (_Float16*)(ws + OFF_XB3);
    _Float16*           xtl  = (_Float16*)(ws + OFF_XTL);
    float*              bias = (float*)(ws + OFF_BIAS);

    (void)hipFuncSetAttribute(reinterpret_cast<const void*>(lstm_persist),
                              hipFuncAttributeMaxDynamicSharedMemorySize, LDS_TOT);

    (void)hipMemsetAsync(hbt, 0, 2 * 256 * 256 * sizeof(unsigned long long), stream);

    prep_wc4<<<(16 * 4 * 2 * 20 * 64 * 8) / 256, 256, 0, stream>>>(Wih, Whh, bih, bhh, Wc, bias);
    prep_x3<<<(S_ * 16 * 3 * 512) / 256, 256, 0, stream>>>(sent, emb, xb3);
    prep_xtail<<<(S_ * B_ * 4) / 256, 256, 0, stream>>>(sent, emb, xtl);
    lstm_persist<<<256, 256, LDS_TOT, stream>>>(Wc, hbt, xb3, xtl, bias, (float*)d_out);
}